// Round 10
// baseline (50.055 us; speedup 1.0000x reference)
//
#include <hip/hip_runtime.h>
#include <hip/hip_bf16.h>

// y = upsample_nearest_2x2x2(conv1x1(x,W,b)); conv on small grid via bf16 MFMA, replicate 8x.
// x: [2][320][16][32][32] f32, W: [160][320] f32, b: [160] f32 -> out: [2][160][32][64][64] f32
//
// v10 = v9 (38.7us) + two changes:
//  (1) 2-chunk-deep register prefetch (two static generations, fully unrolled loop)
//  (2) barrier = inline-asm "s_waitcnt lgkmcnt(0); s_barrier" -> prefetch loads stay
//      in flight across the barrier (no vmcnt(0) drain). LDS visibility: each wave
//      drains its own ds_writes (and ds_reads) via lgkmcnt(0) before the barrier,
//      so buf[bs] reuse at c+2 (guarded by barrier c+1) is race-free.

#define CI     320
#define CO     160
#define S_IN   16384      // 16*32*32
#define KC     32         // K chunk = one MFMA K-step
#define NT     64         // spatial tile per block
#define NCHUNK (CI / KC)  // 10
#define MT     (CO / 16)  // 10 M-tiles

typedef __attribute__((ext_vector_type(8))) short short8;
typedef __attribute__((ext_vector_type(4))) float f32x4;

static __device__ __forceinline__ unsigned short f2bf(float f) {
    __hip_bfloat16 h = __float2bfloat16(f);   // RNE
    unsigned short u;
    __builtin_memcpy(&u, &h, 2);
    return u;
}
static __device__ __forceinline__ unsigned int pack2(float lo, float hi) {
    return (unsigned int)f2bf(lo) | ((unsigned int)f2bf(hi) << 16);
}

__global__ __launch_bounds__(256) void fused_upconv_v10(
    const float* __restrict__ x,
    const float* __restrict__ Wm,
    const float* __restrict__ bias,
    float* __restrict__ out)
{
    // bf16 tiles, rows padded to 80 B (20 u32) — proven layout, x2 buffers (35.8 KB)
    __shared__ unsigned int XsU[2][NT][20];   // [buf][s][k/2]
    __shared__ unsigned int WsU[2][CO][20];   // [buf][o][k/2]

    const int t      = threadIdx.x;
    const int tile   = blockIdx.x;          // 0..255
    const int b      = blockIdx.y;          // 0..1
    const int s_base = tile * NT;
    const float* xb  = x + (size_t)b * CI * S_IN;

    // ---- staging maps (identical to v9) ----
    const int kp = t >> 4;              // k-pair 0..15
    const int s4 = (t & 15) * 4;        // s-quad base
    const int ow = t >> 3;              // W o-base 0..31
    const int kq = t & 7;               // W k-quad 0..7

    float4 xr0[2], xr1[2];
    float4 wr[2][5];

    // ---- prologue: prefetch generations 0 and 1 ----
    #pragma unroll
    for (int g = 0; g < 2; ++g) {
        const int kc = g * KC;
        xr0[g] = *(const float4*)&xb[(size_t)(kc + 2 * kp)     * S_IN + s_base + s4];
        xr1[g] = *(const float4*)&xb[(size_t)(kc + 2 * kp + 1) * S_IN + s_base + s4];
        #pragma unroll
        for (int it = 0; it < 5; ++it)
            wr[g][it] = *(const float4*)&Wm[(size_t)(ow + it * 32) * CI + kc + kq * 4];
    }

    // ---- fragment indices (identical to v9) ----
    const int lane = t & 63;
    const int wid  = t >> 6;        // wave -> 16-s subtile
    const int frow = lane & 15;
    const int fk   = lane >> 4;

    f32x4 acc[MT];
    #pragma unroll
    for (int mt = 0; mt < MT; ++mt) acc[mt] = (f32x4){0.f, 0.f, 0.f, 0.f};

    #pragma unroll
    for (int c = 0; c < NCHUNK; ++c) {
        const int bs = c & 1;       // compile-time after unroll -> static reg indexing

        // stage gen-c regs -> LDS buf[bs] (compiler waits only on gen-c loads)
        {
            const float xa[4] = {xr0[bs].x, xr0[bs].y, xr0[bs].z, xr0[bs].w};
            const float xc[4] = {xr1[bs].x, xr1[bs].y, xr1[bs].z, xr1[bs].w};
            #pragma unroll
            for (int j = 0; j < 4; ++j)
                XsU[bs][s4 + j][kp] = pack2(xa[j], xc[j]);   // k=2kp low, 2kp+1 high
            #pragma unroll
            for (int it = 0; it < 5; ++it) {
                uint2 p = make_uint2(pack2(wr[bs][it].x, wr[bs][it].y),
                                     pack2(wr[bs][it].z, wr[bs][it].w));
                *(uint2*)&WsU[bs][ow + it * 32][kq * 2] = p;
            }
        }

        // issue gen-(c+2) prefetch into the just-freed slot (rides across the barrier)
        if (c + 2 < NCHUNK) {
            const int kc = (c + 2) * KC;
            xr0[bs] = *(const float4*)&xb[(size_t)(kc + 2 * kp)     * S_IN + s_base + s4];
            xr1[bs] = *(const float4*)&xb[(size_t)(kc + 2 * kp + 1) * S_IN + s_base + s4];
            #pragma unroll
            for (int it = 0; it < 5; ++it)
                wr[bs][it] = *(const float4*)&Wm[(size_t)(ow + it * 32) * CI + kc + kq * 4];
        }

        // barrier WITHOUT vmcnt drain: LDS ops complete, prefetch loads stay in flight
        asm volatile("s_waitcnt lgkmcnt(0)\n\ts_barrier" ::: "memory");

        // compute chunk c from buf[bs]
        const short8 bfrag =
            *(const short8*)((const char*)(&XsU[bs][wid * 16 + frow][0]) + fk * 16);
        #pragma unroll
        for (int mt = 0; mt < MT; ++mt) {
            const short8 afrag =
                *(const short8*)((const char*)(&WsU[bs][mt * 16 + frow][0]) + fk * 16);
            acc[mt] = __builtin_amdgcn_mfma_f32_16x16x32_bf16(afrag, bfrag, acc[mt], 0, 0, 0);
        }
        // buf[bs] is rewritten at c+2, which all waves reach only after barrier c+1;
        // each wave's chunk-c ds_reads completed at its own lgkmcnt(0) -> race-free.
    }

    // ---- epilogue (identical to v9): bias + replicate 8x; shfl-pair float4 stores ----
    const int s   = s_base + wid * 16 + frow;   // D col = s
    const int dd  = s >> 10;
    const int hh  = (s >> 5) & 31;
    const int wc  = s & 31;
    const int odd = lane & 1;
    const int wc0 = wc & ~1;

    #pragma unroll
    for (int mt = 0; mt < MT; ++mt) {
        #pragma unroll
        for (int j = 0; j < 4; ++j) {
            const int o = mt * 16 + fk * 4 + j; // D row = o
            float v  = acc[mt][j] + bias[o];
            float vp = __shfl_xor(v, 1);
            float lo = odd ? vp : v;
            float hi = odd ? v : vp;
            float4 q = make_float4(lo, lo, hi, hi);
            const size_t base = (((size_t)(b * CO + o) * 32) + (size_t)(2 * dd + odd)) * 4096
                              + (size_t)(2 * hh) * 64 + (size_t)(2 * wc0);
            *(float4*)&out[base]      = q;
            *(float4*)&out[base + 64] = q;
        }
    }
}

extern "C" void kernel_launch(void* const* d_in, const int* in_sizes, int n_in,
                              void* d_out, int out_size, void* d_ws, size_t ws_size,
                              hipStream_t stream) {
    const float* x    = (const float*)d_in[0];
    const float* Wm   = (const float*)d_in[1];
    const float* bias = (const float*)d_in[2];
    float* out        = (float*)d_out;

    dim3 grid(S_IN / NT, 2);   // (256, 2) = 512 blocks
    dim3 block(256);
    fused_upconv_v10<<<grid, block, 0, stream>>>(x, Wm, bias, out);
}

// Round 11
// 42.427 us; speedup vs baseline: 1.1798x; 1.1798x over previous
//
#include <hip/hip_runtime.h>
#include <hip/hip_bf16.h>

// y = upsample_nearest_2x2x2(conv1x1(x,W,b)); conv on small grid via bf16 MFMA, replicate 8x.
// x: [2][320][16][32][32] f32, W: [160][320] f32, b: [160] f32 -> out: [2][160][32][64][64] f32
//
// v11 = v9 (38.7us) restructured into TWO sequential 32-s passes per block:
// pass 0 {K-loop, store}, pass 1 {K-loop, store}. Pass-0's store burst overlaps
// pass-1's read/stage phase within each wave -> HBM read and write streams mix
// instead of a serial read-phase + write-tail. W staged twice (L2-resident, cheap).
// Barrier scheme identical to v9: one __syncthreads per chunk, bs = cc&1.

#define CI     320
#define CO     160
#define S_IN   16384      // 16*32*32
#define KC     32         // K chunk = one MFMA K-step
#define NT     64         // block s-tile
#define HP     32         // per-pass s
#define NCC    20         // 2 passes x 10 chunks
#define MTW    5          // M-tiles per wave (80 o)

typedef __attribute__((ext_vector_type(8))) short short8;
typedef __attribute__((ext_vector_type(4))) float f32x4;

static __device__ __forceinline__ unsigned short f2bf(float f) {
    __hip_bfloat16 h = __float2bfloat16(f);   // RNE
    unsigned short u;
    __builtin_memcpy(&u, &h, 2);
    return u;
}
static __device__ __forceinline__ unsigned int pack2(float lo, float hi) {
    return (unsigned int)f2bf(lo) | ((unsigned int)f2bf(hi) << 16);
}

__global__ __launch_bounds__(256) void fused_upconv_v11(
    const float* __restrict__ x,
    const float* __restrict__ Wm,
    const float* __restrict__ bias,
    float* __restrict__ out)
{
    // proven 80B-row layout, x2 buffers: X 2x32x20 (5 KB) + W 2x160x20 (25 KB)
    __shared__ unsigned int XsU[2][HP][20];   // [buf][s][k/2]
    __shared__ unsigned int WsU[2][CO][20];   // [buf][o][k/2]

    const int t      = threadIdx.x;
    const int tile   = blockIdx.x;          // 0..255
    const int b      = blockIdx.y;          // 0..1
    const int s_base = tile * NT;
    const float* xb  = x + (size_t)b * CI * S_IN;

    // ---- staging maps ----
    const int kp = t >> 4;              // k-pair 0..15
    const int s2 = (t & 15) * 2;        // s-pair base 0..30
    const int ow = t >> 3;              // W o-base 0..31
    const int kq = t & 7;               // W k-quad 0..7

    float2 xr0, xr1;                    // X: 2 s at k=2kp, 2kp+1
    float4 wr[5];

    // ---- fragment indices ----
    const int lane = t & 63;
    const int wid  = t >> 6;
    const int shh  = wid & 1;           // s-subtile within pass (16 s)
    const int oh   = wid >> 1;          // o-half (80 o)
    const int frow = lane & 15;
    const int fk   = lane >> 4;
    const int o_base = oh * 80;
    const int odd  = lane & 1;

    // prefetch (pass 0, chunk 0)
    xr0 = *(const float2*)&xb[(size_t)(2 * kp)     * S_IN + s_base + s2];
    xr1 = *(const float2*)&xb[(size_t)(2 * kp + 1) * S_IN + s_base + s2];
    #pragma unroll
    for (int it = 0; it < 5; ++it)
        wr[it] = *(const float4*)&Wm[(size_t)(ow + it * 32) * CI + kq * 4];

    f32x4 acc[MTW];
    #pragma unroll
    for (int m = 0; m < MTW; ++m) acc[m] = (f32x4){0.f, 0.f, 0.f, 0.f};

#define EPILOGUE(P)                                                                   \
    {                                                                                 \
        const int s_  = s_base + (P) * HP + shh * 16 + frow;                          \
        const int dd_ = s_ >> 10;                                                     \
        const int hh_ = (s_ >> 5) & 31;                                               \
        const int w0_ = (s_ & 31) & ~1;                                               \
        _Pragma("unroll")                                                             \
        for (int m = 0; m < MTW; ++m) {                                               \
            _Pragma("unroll")                                                         \
            for (int j = 0; j < 4; ++j) {                                             \
                const int o = o_base + m * 16 + fk * 4 + j;                           \
                float v  = acc[m][j] + bias[o];                                       \
                float vp = __shfl_xor(v, 1);                                          \
                float lo = odd ? vp : v;                                              \
                float hi = odd ? v : vp;                                              \
                float4 q = make_float4(lo, lo, hi, hi);                               \
                const size_t base_ = (((size_t)(b * CO + o) * 32)                     \
                                      + (size_t)(2 * dd_ + odd)) * 4096               \
                                   + (size_t)(2 * hh_) * 64 + (size_t)(2 * w0_);      \
                *(float4*)&out[base_]      = q;                                       \
                *(float4*)&out[base_ + 64] = q;                                       \
            }                                                                         \
        }                                                                             \
    }

    #pragma unroll
    for (int cc = 0; cc < NCC; ++cc) {
        const int bs = cc & 1;

        // stage current-gen regs -> LDS buf[bs]
        XsU[bs][s2][kp]     = pack2(xr0.x, xr1.x);
        XsU[bs][s2 + 1][kp] = pack2(xr0.y, xr1.y);
        #pragma unroll
        for (int it = 0; it < 5; ++it) {
            uint2 p = make_uint2(pack2(wr[it].x, wr[it].y), pack2(wr[it].z, wr[it].w));
            *(uint2*)&WsU[bs][ow + it * 32][kq * 2] = p;
        }
        __syncthreads();   // publishes buf[bs]; vmcnt already drained by pack2 uses

        // prefetch next (cc+1): crosses into pass 1 at cc==9 (hides under epilogue 0)
        if (cc + 1 < NCC) {
            const int pn = (cc + 1) / 10;
            const int kc = ((cc + 1) % 10) * KC;
            const size_t so = (size_t)(s_base + pn * HP + s2);
            xr0 = *(const float2*)&xb[(size_t)(kc + 2 * kp)     * S_IN + so];
            xr1 = *(const float2*)&xb[(size_t)(kc + 2 * kp + 1) * S_IN + so];
            #pragma unroll
            for (int it = 0; it < 5; ++it)
                wr[it] = *(const float4*)&Wm[(size_t)(ow + it * 32) * CI + kc + kq * 4];
        }

        // compute chunk from buf[bs]
        const short8 bfrag =
            *(const short8*)((const char*)(&XsU[bs][shh * 16 + frow][0]) + fk * 16);
        #pragma unroll
        for (int m = 0; m < MTW; ++m) {
            const short8 afrag =
                *(const short8*)((const char*)(&WsU[bs][o_base + m * 16 + frow][0]) + fk * 16);
            acc[m] = __builtin_amdgcn_mfma_f32_16x16x32_bf16(afrag, bfrag, acc[m], 0, 0, 0);
        }

        // end of pass 0: store its outputs now (overlaps pass-1 reads), reset acc
        if (cc == 9) {
            EPILOGUE(0);
            #pragma unroll
            for (int m = 0; m < MTW; ++m) acc[m] = (f32x4){0.f, 0.f, 0.f, 0.f};
        }
    }

    EPILOGUE(1);
#undef EPILOGUE
}

extern "C" void kernel_launch(void* const* d_in, const int* in_sizes, int n_in,
                              void* d_out, int out_size, void* d_ws, size_t ws_size,
                              hipStream_t stream) {
    const float* x    = (const float*)d_in[0];
    const float* Wm   = (const float*)d_in[1];
    const float* bias = (const float*)d_in[2];
    float* out        = (float*)d_out;

    dim3 grid(S_IN / NT, 2);   // (256, 2) = 512 blocks
    dim3 block(256);
    fused_upconv_v11<<<grid, block, 0, stream>>>(x, Wm, bias, out);
}